// Round 11
// baseline (1012.473 us; speedup 1.0000x reference)
//
#include <hip/hip_runtime.h>

// ---------- types & helpers ----------
typedef __attribute__((ext_vector_type(8))) short bf16x8;
typedef __attribute__((ext_vector_type(8))) unsigned short ushort8;
typedef __attribute__((ext_vector_type(4))) float f32x4;
typedef __attribute__((ext_vector_type(4))) int i32x4;

__device__ __forceinline__ unsigned short f2bf(float f) {
  union { float f; unsigned u; } v; v.f = f;
  unsigned r = (v.u + 0x7FFFu + ((v.u >> 16) & 1u)) >> 16;
  return (unsigned short)r;
}
__device__ __forceinline__ float bf2f(unsigned short h) {
  union { unsigned u; float f; } v; v.u = ((unsigned)h) << 16;
  return v.f;
}
__device__ __forceinline__ float sigm(float x) { return 1.f / (1.f + __expf(-x)); }
__device__ __forceinline__ float tanh_(float x) { return 1.f - 2.f / (__expf(2.f * x) + 1.f); }

// agent-coherent ops (sc0 sc1): bypass non-coherent per-XCD L2, plain ld/st
// path (no atomics, no compiler fences -> no buffer_wbl2/buffer_inv).
__device__ __forceinline__ i32x4 ld_coh_b128(const void* p) {
  i32x4 r;
  asm volatile("global_load_dwordx4 %0, %1, off sc0 sc1" : "=v"(r) : "v"(p) : "memory");
  return r;
}
__device__ __forceinline__ unsigned ld_coh_u16(const void* p) {
  unsigned r;
  asm volatile("global_load_ushort %0, %1, off sc0 sc1" : "=v"(r) : "v"(p) : "memory");
  return r;
}
__device__ __forceinline__ void st_coh_b128(void* p, i32x4 v) {
  asm volatile("global_store_dwordx4 %0, %1, off sc0 sc1" :: "v"(p), "v"(v) : "memory");
}
__device__ __forceinline__ void st_coh_b16(void* p, unsigned v) {
  asm volatile("global_store_short %0, %1, off sc0 sc1" :: "v"(p), "v"(v) : "memory");
}
__device__ __forceinline__ void wait_vm0_fence() {
  asm volatile("s_waitcnt vmcnt(0)" ::: "memory");
  __builtin_amdgcn_sched_barrier(0);   // rule #18: nothing hoists past the asm waitcnt
}

#define GLDS(g, l) __builtin_amdgcn_global_load_lds( \
    (const __attribute__((address_space(1))) unsigned int*)(g), \
    (__attribute__((address_space(3))) unsigned int*)(l), 16, 0, 0)

// ---------- fused prep: gather (to [t][b] rows) + h0 + W_ih conv + W_out conv ----------
__global__ __launch_bounds__(256) void prep(
    const int* __restrict__ x, const float* __restrict__ emb, unsigned short* __restrict__ xe,
    const float* __restrict__ z, const float* __restrict__ Wi, const float* __restrict__ bi,
    float* __restrict__ h0f, unsigned short* __restrict__ hb16,
    const float* __restrict__ Wih, unsigned short* __restrict__ WihB,
    const float* __restrict__ Wout, unsigned short* __restrict__ WoutB) {
  const int tid = threadIdx.x;
  const unsigned bid = blockIdx.x;
  if (bid < 2048) {                      // gather: 2 rows per block, row r = t*16+b
    const int r = (bid << 1) + (tid >> 7);
    const int b = r & 15, t = r >> 4;
    const int tok = x[b * 256 + t];
    const int c = tid & 127;
    const float4 v = ((const float4*)(emb + (size_t)tok * 512))[c];
    ushort4 o; o.x = f2bf(v.x); o.y = f2bf(v.y); o.z = f2bf(v.z); o.w = f2bf(v.w);
    ((ushort4*)(xe + (size_t)r * 512))[c] = o;
  } else if (bid < 2112) {               // h0 = tanh(z @ Wi^T + bi)
    const int idx = (bid - 2048) * 256 + tid;          // 0..16383
    const int b = idx & 15, i = idx >> 4;
    const float4* wr = (const float4*)(Wi + (size_t)i * 1024);
    const float4* zr = (const float4*)(z + (size_t)b * 1024);
    float acc = bi[i];
#pragma unroll 4
    for (int k = 0; k < 256; ++k) {
      float4 w = wr[k], zv = zr[k];
      acc += w.x * zv.x + w.y * zv.y + w.z * zv.z + w.w * zv.w;
    }
    const float h = tanh_(acc);
    h0f[(size_t)b * 1024 + i] = h;
    hb16[((i >> 4) << 8) + (b << 4) + (i & 15)] = f2bf(h);   // [slot0][j][b][c]
  } else if (bid < 3648) {               // W_ih conversion
    const int i = (int)(bid - 2112) * 256 + tid;       // < 393216
    const float4 v = ((const float4*)Wih)[i];
    ushort4 o; o.x = f2bf(v.x); o.y = f2bf(v.y); o.z = f2bf(v.z); o.w = f2bf(v.w);
    ((ushort4*)WihB)[i] = o;
  } else {                               // W_out conversion (grid-stride, 512 blocks)
    for (int i = (int)(bid - 3648) * 256 + tid; i < 32000 * 1024 / 4; i += 512 * 256) {
      const float4 v = ((const float4*)Wout)[i];
      ushort4 o; o.x = f2bf(v.x); o.y = f2bf(v.y); o.z = f2bf(v.z); o.w = f2bf(v.w);
      ((ushort4*)WoutB)[i] = o;
    }
  }
}

// ---------- mega: GRU (0..63) + gi GEMM (64..831) + logits GEMM (832..2831) ----------
// gi rows = [t*16+b]: M-tile tm covers t in [8tm,8tm+8). gi blocks release via
// coherent C stores -> vmcnt(0) -> barrier -> agent atomicAdd(gicnt[tm]) (proven
// release pattern). gru step-wait polls h-flags AND gicnt[t>>3]==24; gi values
// read coherently in the same latency round as the h loads.
// Logits tile bm needs hs rows t in [16bm,16bm+16): flag >= 16bm+17 (or 1024).
__global__ __launch_bounds__(512, 1) void mega(
    const float* __restrict__ Whh, const float* __restrict__ bhh,
    unsigned short* __restrict__ gi, const float* __restrict__ h0f,
    unsigned short* __restrict__ hb16, unsigned short* __restrict__ hs,
    unsigned int* __restrict__ flags, unsigned int* __restrict__ gicnt,
    const unsigned short* __restrict__ xe, const unsigned short* __restrict__ WihB,
    const float* __restrict__ bih,
    const unsigned short* __restrict__ WoutB, const float* __restrict__ bout,
    float* __restrict__ out) {
  __shared__ __align__(16) char lds[65536];
  const int tid = threadIdx.x, lane = tid & 63, wave = tid >> 6;

  if (blockIdx.x < 64) {
    // ================= GRU recurrence =======================================
    const int j = blockIdx.x;
    if (tid >= 256) {                       // waves 4-7: barrier-matching only
      for (int t = 0; t < 256; ++t) { __syncthreads(); if (t < 255) __syncthreads(); }
      __syncthreads();
      return;
    }
    float (*ghp)[16][48] = (float (*)[16][48])lds;                 // 12 KB
    unsigned short (*hsl)[16] = (unsigned short (*)[16])(lds + 12288);

    const int lr = lane & 15;
    const int hi8 = (lane >> 4) << 3;
    const int kw = wave << 8;

    bf16x8 wf[3][8];
#pragma unroll
    for (int n = 0; n < 3; ++n) {
      const float* wrow = Whh + (size_t)(n * 1024 + (j << 4) + lr) * 1024 + kw + hi8;
#pragma unroll
      for (int ki = 0; ki < 8; ++ki) {
        const float4 u = *(const float4*)(wrow + ki * 32);
        const float4 v = *(const float4*)(wrow + ki * 32 + 4);
        bf16x8 w;
        w[0] = (short)f2bf(u.x); w[1] = (short)f2bf(u.y);
        w[2] = (short)f2bf(u.z); w[3] = (short)f2bf(u.w);
        w[4] = (short)f2bf(v.x); w[5] = (short)f2bf(v.y);
        w[6] = (short)f2bf(v.z); w[7] = (short)f2bf(v.w);
        wf[n][ki] = w;
      }
    }

    const int b = tid >> 4, c = tid & 15;
    const int cg = (j << 4) + c;
    float hreg = h0f[(size_t)b * 1024 + cg];
    const float br = bhh[cg], bz = bhh[1024 + cg], bn = bhh[2048 + cg];

    for (int t = 0; t < 256; ++t) {
      {  // wait: h flags >= t (t>0) AND gi tile for step t complete
        long guard = 0;
        for (;;) {
          bool ok = true;
          if (t > 0) {
            const unsigned f = __hip_atomic_load(&flags[lane << 5], __ATOMIC_RELAXED,
                                                 __HIP_MEMORY_SCOPE_AGENT);
            ok = (f >= (unsigned)t);
          }
          const unsigned g2 = __hip_atomic_load(&gicnt[(t >> 3) << 5], __ATOMIC_RELAXED,
                                                __HIP_MEMORY_SCOPE_AGENT);
          ok = ok && (g2 >= 24u);
          if (__all(ok)) break;
          __builtin_amdgcn_s_sleep(1);
          if (++guard > (1L << 20)) break;
        }
      }

      // issue h-fragment loads + gi loads in ONE latency round, then fence
      const unsigned short* base = hb16 + ((t & 1) << 14);
      i32x4 hv[8];
#pragma unroll
      for (int ki = 0; ki < 8; ++ki) {
        const int kk = kw + (ki << 5) + hi8;
        hv[ki] = ld_coh_b128(base + ((kk >> 4) << 8) + (lr << 4) + (kk & 15));
      }
      const char* gbase = (const char*)gi + ((size_t)((t << 4) + b) * 3072 + cg) * 2;
      const unsigned uir = ld_coh_u16(gbase);
      const unsigned uiz = ld_coh_u16(gbase + 2048);
      const unsigned uin = ld_coh_u16(gbase + 4096);
      wait_vm0_fence();

      f32x4 acc[3] = {};
#pragma unroll
      for (int ki = 0; ki < 8; ++ki) {
        const bf16x8 af = __builtin_bit_cast(bf16x8, hv[ki]);
#pragma unroll
        for (int n = 0; n < 3; ++n)
          acc[n] = __builtin_amdgcn_mfma_f32_16x16x32_bf16(af, wf[n][ki], acc[n], 0, 0, 0);
      }
#pragma unroll
      for (int n = 0; n < 3; ++n)
#pragma unroll
        for (int q = 0; q < 4; ++q)
          ghp[wave][(lane >> 4) * 4 + q][n * 16 + lr] = acc[n][q];
      __syncthreads();                                    // BAR1

      const float ir = bf2f((unsigned short)uir);
      const float iz = bf2f((unsigned short)uiz);
      const float inn = bf2f((unsigned short)uin);
      const float hr = ghp[0][b][c]      + ghp[1][b][c]      + ghp[2][b][c]      + ghp[3][b][c];
      const float hz = ghp[0][b][16 + c] + ghp[1][b][16 + c] + ghp[2][b][16 + c] + ghp[3][b][16 + c];
      const float hn = ghp[0][b][32 + c] + ghp[1][b][32 + c] + ghp[2][b][32 + c] + ghp[3][b][32 + c];
      const float rg = sigm(ir + hr + br);
      const float zg = sigm(iz + hz + bz);
      const float ng = tanh_(inn + rg * (hn + bn));
      const float hprev = hreg;
      hreg = (1.f - zg) * ng + zg * hprev;

      if (t < 255) {
        hsl[b][c] = f2bf(hreg);
        __syncthreads();                                  // BAR2
        unsigned short* nb = hb16 + (((t + 1) & 1) << 14) + (j << 8);
        if (tid < 32) {
          const i32x4 v = *(const i32x4*)&hsl[tid >> 1][(tid & 1) << 3];
          st_coh_b128(nb + (tid << 3), v);
        }
        if (wave == 0)
          asm volatile("s_waitcnt vmcnt(0)" ::: "memory");
        if (tid == 0)
          __hip_atomic_store(&flags[j << 5], (unsigned)(t + 1),
                             __ATOMIC_RELAXED, __HIP_MEMORY_SCOPE_AGENT);
      }

      // hs in [t][b] layout, coherent (consumed by concurrent GEMM blocks)
      st_coh_b16(hs + ((size_t)((t << 4) + b) << 10) + cg, (unsigned)f2bf(hprev));
    }
    // final drain + done sentinel
    asm volatile("s_waitcnt vmcnt(0)" ::: "memory");
    __syncthreads();
    if (tid == 0)
      __hip_atomic_store(&flags[j << 5], 1024u, __ATOMIC_RELAXED, __HIP_MEMORY_SCOPE_AGENT);
    return;
  }

  if (blockIdx.x < 832) {
    // ================= gi GEMM: 128x128x512 tile, 8 waves ===================
    const int g = blockIdx.x - 64;                 // 0..767
    const int tm = g / 24, tn = g % 24;            // low tm first (gru order)
    const long row0 = (long)tm << 7, col0 = (long)tn << 7;
    char* As = lds;                                // 8 KB
    char* Bs = lds + 8192;                         // 8 KB
    char* Ct = lds + 16384;                        // 32 KB bf16 [128][128]

    const int sr = tid >> 2, sk = (tid & 3) << 3;  // staging row / k-elem
    const unsigned short* Abase = xe + (row0 + sr) * 512 + sk;
    const unsigned short* Bbase = WihB + (col0 + sr) * 512 + sk;
    char* ldsA = As + wave * 1024;
    char* ldsB = Bs + wave * 1024;

    const int wm2 = (wave >> 2) << 6, wn2 = (wave & 3) << 5;   // 2x4 wave tiles
    const int lr = lane & 15, lk = (lane >> 4) << 3;
    f32x4 acc[4][2] = {};

    for (int k0 = 0; k0 < 512; k0 += 32) {
      __syncthreads();
      GLDS(Abase + k0, ldsA);
      GLDS(Bbase + k0, ldsB);
      __syncthreads();
      bf16x8 af[4], bfr[2];
#pragma unroll
      for (int i = 0; i < 4; ++i)
        af[i] = *(const bf16x8*)(As + ((wm2 + i * 16 + lr) * 32 + lk) * 2);
#pragma unroll
      for (int jj = 0; jj < 2; ++jj)
        bfr[jj] = *(const bf16x8*)(Bs + ((wn2 + jj * 16 + lr) * 32 + lk) * 2);
#pragma unroll
      for (int i = 0; i < 4; ++i)
#pragma unroll
        for (int jj = 0; jj < 2; ++jj)
          acc[i][jj] = __builtin_amdgcn_mfma_f32_16x16x32_bf16(af[i], bfr[jj], acc[i][jj], 0, 0, 0);
    }

    // stage C tile to LDS (+bias), then coherent 16B stores, then release
    const int lq = (lane >> 4) << 2;
    float bias0 = bih[col0 + wn2 + lr], bias1 = bih[col0 + wn2 + 16 + lr];
    __syncthreads();
#pragma unroll
    for (int i = 0; i < 4; ++i)
#pragma unroll
      for (int jj = 0; jj < 2; ++jj)
#pragma unroll
        for (int q = 0; q < 4; ++q)
          *(unsigned short*)(Ct + (wm2 + i * 16 + lq + q) * 256
                                + ((wn2 + jj * 16 + lr) << 1)) =
              f2bf(acc[i][jj][q] + (jj ? bias1 : bias0));
    __syncthreads();
#pragma unroll
    for (int k2 = 0; k2 < 4; ++k2) {
      const int s2 = (k2 << 9) + tid;              // 0..2047
      const int row = s2 >> 4, colb = (s2 & 15) << 4;
      st_coh_b128((char*)gi + (size_t)(row0 + row) * 6144 + (col0 << 1) + colb,
                  *(const i32x4*)(Ct + row * 256 + colb));
    }
    asm volatile("s_waitcnt vmcnt(0)" ::: "memory");
    __syncthreads();                               // all threads' stores acked
    if (tid == 0)
      __hip_atomic_fetch_add(&gicnt[tm << 5], 1u, __ATOMIC_RELAXED,
                             __HIP_MEMORY_SCOPE_AGENT);
    return;
  }

  // ================= logits GEMM: 256x256 tile, counted-vmcnt pipeline ======
  const int gb = blockIdx.x - 832;
  const int bm = gb / 125, bn = gb % 125;        // bm monotone in dispatch order
  const long row0 = (long)bm << 8, col0 = (long)bn << 8;

  {   // wait for hs rows [16bm, 16bm+16) to be globally visible
    unsigned thr = (unsigned)(16 * bm + 17); if (thr > 255u) thr = 1024u;
    if (wave == 0) {
      long guard = 0;
      for (;;) {
        const unsigned f = __hip_atomic_load(&flags[lane << 5], __ATOMIC_RELAXED,
                                             __HIP_MEMORY_SCOPE_AGENT);
        if (__all(f >= thr)) break;
        __builtin_amdgcn_s_sleep(32);
        if (++guard > (1L << 22)) break;
      }
    }
    __syncthreads();
  }

  const int wm = wave >> 2, wn = wave & 3;          // 2 x 4 waves
  // A staging: coherent reg-load -> swizzled ds_write (256 rows x 64B / step)
  const int arow = tid >> 1, ahalf = (tid & 1) << 5;
  const char* Ab = (const char*)hs + ((row0 + arow) << 11) + ahalf;
  const int awz0 = ((arow << 6) + ahalf) ^ ((arow & 12) << 2);
  const int awz1 = ((arow << 6) + ahalf + 16) ^ ((arow & 12) << 2);
  // B staging: GLDS with inverse-swizzled source
  const int srow = tid >> 2, skb = (tid & 3) << 4;
  auto stageB = [&](int sp, int rr) {
    const int row = (rr << 7) + srow;
    const int kbu = skb ^ ((row & 12) << 2);
    const char* g = (const char*)WoutB + ((col0 + row) << 11) + (sp << 6) + kbu;
    char* l = lds + ((sp & 1) << 15) + 16384 + (rr << 13) + (wave << 10);
    GLDS(g, l);
  };
  const int lr = lane & 15, ko = (lane >> 4) << 4;
  auto rdA = [&](int buf, int mrep) {
    const int rt = (wm << 7) + (mrep << 4) + lr;
    const int a = (rt << 6) + ko;
    return *(const bf16x8*)(lds + (buf << 15) + (a ^ ((rt & 12) << 2)));
  };
  auto rdB = [&](int buf, int nrep) {
    const int rt = (wn << 6) + (nrep << 4) + lr;
    const int a = (rt << 6) + ko;
    return *(const bf16x8*)(lds + (buf << 15) + 16384 + (a ^ ((rt & 12) << 2)));
  };

  f32x4 acc[8][4] = {};
  i32x4 rA0 = ld_coh_b128(Ab);                     // A(0) -> regs
  i32x4 rA1 = ld_coh_b128(Ab + 16);
  stageB(0, 0); stageB(0, 1);

  for (int s = 0; s < 32; ++s) {
    const int buf = s & 1;
    if (s < 31) {
      stageB(s + 1, 0); stageB(s + 1, 1);          // into buf^1
      asm volatile("s_waitcnt vmcnt(2)" ::: "memory");   // A(s) regs + B(s) LDS done
    } else {
      asm volatile("s_waitcnt vmcnt(0)" ::: "memory");
    }
    __builtin_amdgcn_sched_barrier(0);
    *(i32x4*)(lds + (buf << 15) + awz0) = rA0;     // commit A(s) swizzled
    *(i32x4*)(lds + (buf << 15) + awz1) = rA1;
    if (s < 31) {
      rA0 = ld_coh_b128(Ab + ((s + 1) << 6));      // A(s+1) -> regs
      rA1 = ld_coh_b128(Ab + ((s + 1) << 6) + 16);
    }
    asm volatile("s_waitcnt lgkmcnt(0)" ::: "memory");
    __builtin_amdgcn_sched_barrier(0);
    __builtin_amdgcn_s_barrier();                  // buf fully valid

    bf16x8 bfr[4], af[4], af2[4];
#pragma unroll
    for (int n = 0; n < 4; ++n) bfr[n] = rdB(buf, n);
#pragma unroll
    for (int m = 0; m < 4; ++m) af[m] = rdA(buf, m);
    asm volatile("s_waitcnt lgkmcnt(0)" ::: "memory");
    __builtin_amdgcn_sched_barrier(0);
    __builtin_amdgcn_s_setprio(1);
#pragma unroll
    for (int m = 0; m < 4; ++m)
#pragma unroll
      for (int n = 0; n < 4; ++n)
        acc[m][n] = __builtin_amdgcn_mfma_f32_16x16x32_bf16(af[m], bfr[n], acc[m][n], 0, 0, 0);
    __builtin_amdgcn_s_setprio(0);
#pragma unroll
    for (int m = 0; m < 4; ++m) af2[m] = rdA(buf, m + 4);
    asm volatile("s_waitcnt lgkmcnt(0)" ::: "memory");
    __builtin_amdgcn_sched_barrier(0);
    __builtin_amdgcn_s_barrier();                  // all reads of buf done
    __builtin_amdgcn_s_setprio(1);
#pragma unroll
    for (int m = 0; m < 4; ++m)
#pragma unroll
      for (int n = 0; n < 4; ++n)
        acc[m + 4][n] = __builtin_amdgcn_mfma_f32_16x16x32_bf16(af2[m], bfr[n], acc[m + 4][n], 0, 0, 0);
    __builtin_amdgcn_s_setprio(0);
  }

  // epilogue: A row ar = t*16+b  ->  C row = b*256+t
  const int lq = (lane >> 4) << 2;
#pragma unroll
  for (int mr = 0; mr < 8; ++mr) {
#pragma unroll
    for (int q = 0; q < 4; ++q) {
      const int ar = (int)row0 + (wm << 7) + (mr << 4) + lq + q;
      const int tt = ar >> 4, bb = ar & 15;
      float* crow = out + ((size_t)bb * 256 + tt) * 32000;
#pragma unroll
      for (int nr = 0; nr < 4; ++nr) {
        const long cc = col0 + (wn << 6) + (nr << 4) + lr;
        crow[cc] = acc[mr][nr][q] + bout[cc];
      }
    }
  }
}

// ---------- launch ----------
extern "C" void kernel_launch(void* const* d_in, const int* in_sizes, int n_in,
                              void* d_out, int out_size, void* d_ws, size_t ws_size,
                              hipStream_t stream) {
  const float* z     = (const float*)d_in[0];
  const int*   x     = (const int*)d_in[1];
  const float* emb   = (const float*)d_in[2];
  const float* Winit = (const float*)d_in[3];
  const float* binit = (const float*)d_in[4];
  const float* Wih   = (const float*)d_in[5];
  const float* Whh   = (const float*)d_in[6];
  const float* bih   = (const float*)d_in[7];
  const float* bhh   = (const float*)d_in[8];
  const float* Wout  = (const float*)d_in[9];
  const float* bout  = (const float*)d_in[10];
  float* out = (float*)d_out;

  char* ws = (char*)d_ws;
  size_t off = 0;
  auto alloc = [&](size_t bytes) { void* p = ws + off; off += (bytes + 255) & ~(size_t)255; return p; };
  unsigned int*   flags = (unsigned int*)alloc(64 * 128);       // h-step flags
  unsigned int*   gicnt = (unsigned int*)alloc(32 * 128);       // gi tile counters
  unsigned short* xe    = (unsigned short*)alloc((size_t)4096 * 512 * 2);
  unsigned short* WihB  = (unsigned short*)alloc((size_t)3072 * 512 * 2);
  unsigned short* WoutB = (unsigned short*)alloc((size_t)32000 * 1024 * 2);
  unsigned short* giB   = (unsigned short*)alloc((size_t)4096 * 3072 * 2);
  unsigned short* hsB   = (unsigned short*)alloc((size_t)4096 * 1024 * 2);
  float*          h0f   = (float*)alloc((size_t)16 * 1024 * 4);
  unsigned short* hb16  = (unsigned short*)alloc((size_t)2 * 16 * 1024 * 2);
  (void)ws_size; (void)in_sizes; (void)n_in; (void)out_size;

  hipMemsetAsync(flags, 0, 64 * 128 + 32 * 128, stream);        // flags + gicnt

  // prep: gather([t][b] rows) + h0 + W_ih conv + W_out conv
  prep<<<dim3(4160), 256, 0, stream>>>(x, emb, xe, z, Winit, binit, h0f, hb16,
                                       Wih, WihB, Wout, WoutB);

  // fused: GRU (0-63) + gi GEMM (64-831) + logits GEMM (832-2831)
  mega<<<dim3(2832), 512, 0, stream>>>(Whh, bhh, giB, h0f, hb16, hsB, flags, gicnt,
                                       xe, WihB, bih, WoutB, bout, out);
}

// Round 12
// 864.078 us; speedup vs baseline: 1.1717x; 1.1717x over previous
//
#include <hip/hip_runtime.h>

// ---------- types & helpers ----------
typedef __attribute__((ext_vector_type(8))) short bf16x8;
typedef __attribute__((ext_vector_type(8))) unsigned short ushort8;
typedef __attribute__((ext_vector_type(4))) float f32x4;
typedef __attribute__((ext_vector_type(4))) int i32x4;

__device__ __forceinline__ unsigned short f2bf(float f) {
  union { float f; unsigned u; } v; v.f = f;
  unsigned r = (v.u + 0x7FFFu + ((v.u >> 16) & 1u)) >> 16;
  return (unsigned short)r;
}
__device__ __forceinline__ float bf2f(unsigned short h) {
  union { unsigned u; float f; } v; v.u = ((unsigned)h) << 16;
  return v.f;
}
__device__ __forceinline__ float sigm(float x) { return 1.f / (1.f + __expf(-x)); }
__device__ __forceinline__ float tanh_(float x) { return 1.f - 2.f / (__expf(2.f * x) + 1.f); }

// agent-coherent ops (sc0 sc1): bypass non-coherent per-XCD L2, plain ld/st
// path (no atomics, no compiler fences -> no buffer_wbl2/buffer_inv).
__device__ __forceinline__ i32x4 ld_coh_b128(const void* p) {
  i32x4 r;
  asm volatile("global_load_dwordx4 %0, %1, off sc0 sc1" : "=v"(r) : "v"(p) : "memory");
  return r;
}
__device__ __forceinline__ void st_coh_b128(void* p, i32x4 v) {
  asm volatile("global_store_dwordx4 %0, %1, off sc0 sc1" :: "v"(p), "v"(v) : "memory");
}
__device__ __forceinline__ void st_coh_b16(void* p, unsigned v) {
  asm volatile("global_store_short %0, %1, off sc0 sc1" :: "v"(p), "v"(v) : "memory");
}
__device__ __forceinline__ void wait_vm0_fence() {
  asm volatile("s_waitcnt vmcnt(0)" ::: "memory");
  __builtin_amdgcn_sched_barrier(0);   // rule #18: nothing hoists past the asm waitcnt
}

#define GLDS(g, l) __builtin_amdgcn_global_load_lds( \
    (const __attribute__((address_space(1))) unsigned int*)(g), \
    (__attribute__((address_space(3))) unsigned int*)(l), 16, 0, 0)

// ---------- fused prep: embedding gather + h0 + W_ih conv + W_out conv ----------
__global__ __launch_bounds__(256) void prep(
    const int* __restrict__ x, const float* __restrict__ emb, unsigned short* __restrict__ xe,
    const float* __restrict__ z, const float* __restrict__ Wi, const float* __restrict__ bi,
    float* __restrict__ h0f, unsigned short* __restrict__ hb16,
    const float* __restrict__ Wih, unsigned short* __restrict__ WihB,
    const float* __restrict__ Wout, unsigned short* __restrict__ WoutB) {
  const int tid = threadIdx.x;
  const unsigned bid = blockIdx.x;
  if (bid < 2048) {                      // gather: 2 tokens per block
    const int m = (bid << 1) + (tid >> 7);
    const int tok = x[m];
    const int c = tid & 127;
    const float4 v = ((const float4*)(emb + (size_t)tok * 512))[c];
    ushort4 o; o.x = f2bf(v.x); o.y = f2bf(v.y); o.z = f2bf(v.z); o.w = f2bf(v.w);
    ((ushort4*)(xe + (size_t)m * 512))[c] = o;
  } else if (bid < 2112) {               // h0 = tanh(z @ Wi^T + bi)
    const int idx = (bid - 2048) * 256 + tid;          // 0..16383
    const int b = idx & 15, i = idx >> 4;
    const float4* wr = (const float4*)(Wi + (size_t)i * 1024);
    const float4* zr = (const float4*)(z + (size_t)b * 1024);
    float acc = bi[i];
#pragma unroll 4
    for (int k = 0; k < 256; ++k) {
      float4 w = wr[k], zv = zr[k];
      acc += w.x * zv.x + w.y * zv.y + w.z * zv.z + w.w * zv.w;
    }
    const float h = tanh_(acc);
    h0f[(size_t)b * 1024 + i] = h;
    hb16[((i >> 4) << 8) + (b << 4) + (i & 15)] = f2bf(h);   // [slot0][j][b][c]
  } else if (bid < 3648) {               // W_ih conversion
    const int i = (int)(bid - 2112) * 256 + tid;       // < 393216
    const float4 v = ((const float4*)Wih)[i];
    ushort4 o; o.x = f2bf(v.x); o.y = f2bf(v.y); o.z = f2bf(v.z); o.w = f2bf(v.w);
    ((ushort4*)WihB)[i] = o;
  } else {                               // W_out conversion (grid-stride)
    for (int i = (int)(bid - 3648) * 256 + tid; i < 32000 * 1024 / 4; i += 512 * 256) {
      const float4 v = ((const float4*)Wout)[i];
      ushort4 o; o.x = f2bf(v.x); o.y = f2bf(v.y); o.z = f2bf(v.z); o.w = f2bf(v.w);
      ((ushort4*)WoutB)[i] = o;
    }
  }
}

// ---------- bf16 GEMM (m97 128x128 + XCD swizzle) -- gi projection ----------
__global__ __launch_bounds__(256) void gemm_bt(
    const unsigned short* __restrict__ A, const unsigned short* __restrict__ Bm,
    const float* __restrict__ bias, unsigned short* __restrict__ C,
    int M, int N, int K) {
  __shared__ __align__(16) unsigned short As[128 * 32];
  __shared__ __align__(16) unsigned short Bs[128 * 32];
  const int tid = threadIdx.x;
  const int lane = tid & 63, wave = tid >> 6;
  const int nTM = M >> 7;
  const int nwg = (int)gridDim.x;
  int wg = blockIdx.x;
  if ((nwg & 7) == 0) wg = (wg & 7) * (nwg >> 3) + (wg >> 3);
  const int bm = wg % nTM, bn = wg / nTM;
  const long row0 = (long)bm << 7, col0 = (long)bn << 7;
  const int wm = (wave & 1) << 6, wn = (wave >> 1) << 6;

  f32x4 acc[4][4] = {};

  const int sr = (wave << 4) + (lane >> 2);
  const int sk = (lane & 3) << 3;
  const unsigned short* Abase = A + ((size_t)(row0 + sr)) * K + sk;
  const unsigned short* Bbase = Bm + ((size_t)(col0 + sr)) * K + sk;
  char* ldsA = (char*)As + wave * 1024;
  char* ldsB = (char*)Bs + wave * 1024;

  for (int k0 = 0; k0 < K; k0 += 32) {
    __syncthreads();
    GLDS(Abase + k0, ldsA);
    GLDS(Abase + (size_t)64 * K + k0, ldsA + 4096);
    GLDS(Bbase + k0, ldsB);
    GLDS(Bbase + (size_t)64 * K + k0, ldsB + 4096);
    __syncthreads();
    const int lr = lane & 15, lk = (lane >> 4) << 3;
    bf16x8 af[4], bfr[4];
#pragma unroll
    for (int i = 0; i < 4; ++i) {
      af[i]  = *(const bf16x8*)(As + (wm + i * 16 + lr) * 32 + lk);
      bfr[i] = *(const bf16x8*)(Bs + (wn + i * 16 + lr) * 32 + lk);
    }
#pragma unroll
    for (int i = 0; i < 4; ++i)
#pragma unroll
      for (int j = 0; j < 4; ++j)
        acc[i][j] = __builtin_amdgcn_mfma_f32_16x16x32_bf16(af[i], bfr[j], acc[i][j], 0, 0, 0);
  }

  const int lr = lane & 15, lq = (lane >> 4) << 2;
#pragma unroll
  for (int i = 0; i < 4; ++i) {
#pragma unroll
    for (int q = 0; q < 4; ++q) {
      const long r = row0 + wm + i * 16 + lq + q;
      unsigned short* crow = C + (size_t)r * N;
#pragma unroll
      for (int j = 0; j < 4; ++j) {
        const long cc = col0 + wn + j * 16 + lr;
        crow[cc] = f2bf(acc[i][j][q] + bias[cc]);
      }
    }
  }
}

// ---------- mega: persistent GRU (blocks 0..63) + 192 persistent logits workers ----------
// GRU: round-8 proven protocol verbatim. Logits: workers pop tiles from an
// agent-scope atomic queue (oldest strip first); all 256 blocks co-resident,
// so the final strip starts the moment its flags arrive (no dispatch drain).
// Tile bm needs hs rows t in [16bm,16bm+16): flag >= 16bm+17 (or sentinel 1024).
__global__ __launch_bounds__(512, 1) void mega(
    const float* __restrict__ Whh, const float* __restrict__ bhh,
    const unsigned short* __restrict__ gi, const float* __restrict__ h0f,
    unsigned short* __restrict__ hb16, unsigned short* __restrict__ hs,
    unsigned int* __restrict__ flags, unsigned int* __restrict__ qhead,
    const unsigned short* __restrict__ WoutB, const float* __restrict__ bout,
    float* __restrict__ out) {
  __shared__ __align__(16) char lds[65536];
  const int tid = threadIdx.x, lane = tid & 63, wave = tid >> 6;

  if (blockIdx.x < 64) {
    // ================= GRU recurrence (round-8 proven, verbatim) ============
    const int j = blockIdx.x;
    if (tid >= 256) {                       // waves 4-7: barrier-matching only
      for (int t = 0; t < 256; ++t) { __syncthreads(); if (t < 255) __syncthreads(); }
      __syncthreads();
      return;
    }
    float (*ghp)[16][48] = (float (*)[16][48])lds;                 // 12 KB
    unsigned short (*hsl)[16] = (unsigned short (*)[16])(lds + 12288);

    const int lr = lane & 15;
    const int hi8 = (lane >> 4) << 3;
    const int kw = wave << 8;

    bf16x8 wf[3][8];
#pragma unroll
    for (int n = 0; n < 3; ++n) {
      const float* wrow = Whh + (size_t)(n * 1024 + (j << 4) + lr) * 1024 + kw + hi8;
#pragma unroll
      for (int ki = 0; ki < 8; ++ki) {
        const float4 u = *(const float4*)(wrow + ki * 32);
        const float4 v = *(const float4*)(wrow + ki * 32 + 4);
        bf16x8 w;
        w[0] = (short)f2bf(u.x); w[1] = (short)f2bf(u.y);
        w[2] = (short)f2bf(u.z); w[3] = (short)f2bf(u.w);
        w[4] = (short)f2bf(v.x); w[5] = (short)f2bf(v.y);
        w[6] = (short)f2bf(v.z); w[7] = (short)f2bf(v.w);
        wf[n][ki] = w;
      }
    }

    const int b = tid >> 4, c = tid & 15;
    const int cg = (j << 4) + c;
    float hreg = h0f[(size_t)b * 1024 + cg];
    const float br = bhh[cg], bz = bhh[1024 + cg], bn = bhh[2048 + cg];

    const unsigned short* gr0 = gi + ((size_t)b * 256 + 0) * 3072;
    float ir = bf2f(gr0[cg]), iz = bf2f(gr0[1024 + cg]), inn = bf2f(gr0[2048 + cg]);

    for (int t = 0; t < 256; ++t) {
      if (t > 0) {
        long guard = 0;
        for (;;) {
          const unsigned f = __hip_atomic_load(&flags[lane << 5], __ATOMIC_RELAXED,
                                               __HIP_MEMORY_SCOPE_AGENT);
          if (__all(f >= (unsigned)t)) break;
          __builtin_amdgcn_s_sleep(1);
          if (++guard > (1L << 20)) break;
        }
      }

      const unsigned short* base = hb16 + ((t & 1) << 14);
      i32x4 hv[8];
#pragma unroll
      for (int ki = 0; ki < 8; ++ki) {
        const int kk = kw + (ki << 5) + hi8;
        hv[ki] = ld_coh_b128(base + ((kk >> 4) << 8) + (lr << 4) + (kk & 15));
      }
      wait_vm0_fence();

      f32x4 acc[3] = {};
#pragma unroll
      for (int ki = 0; ki < 8; ++ki) {
        const bf16x8 af = __builtin_bit_cast(bf16x8, hv[ki]);
#pragma unroll
        for (int n = 0; n < 3; ++n)
          acc[n] = __builtin_amdgcn_mfma_f32_16x16x32_bf16(af, wf[n][ki], acc[n], 0, 0, 0);
      }
#pragma unroll
      for (int n = 0; n < 3; ++n)
#pragma unroll
        for (int q = 0; q < 4; ++q)
          ghp[wave][(lane >> 4) * 4 + q][n * 16 + lr] = acc[n][q];
      __syncthreads();                                    // BAR1

      const float hr = ghp[0][b][c]      + ghp[1][b][c]      + ghp[2][b][c]      + ghp[3][b][c];
      const float hz = ghp[0][b][16 + c] + ghp[1][b][16 + c] + ghp[2][b][16 + c] + ghp[3][b][16 + c];
      const float hn = ghp[0][b][32 + c] + ghp[1][b][32 + c] + ghp[2][b][32 + c] + ghp[3][b][32 + c];
      const float rg = sigm(ir + hr + br);
      const float zg = sigm(iz + hz + bz);
      const float ng = tanh_(inn + rg * (hn + bn));
      const float hprev = hreg;
      hreg = (1.f - zg) * ng + zg * hprev;

      if (t < 255) {
        hsl[b][c] = f2bf(hreg);
        __syncthreads();                                  // BAR2
        unsigned short* nb = hb16 + (((t + 1) & 1) << 14) + (j << 8);
        if (tid < 32) {
          const i32x4 v = *(const i32x4*)&hsl[tid >> 1][(tid & 1) << 3];
          st_coh_b128(nb + (tid << 3), v);
        }
        if (wave == 0)
          asm volatile("s_waitcnt vmcnt(0)" ::: "memory");
        if (tid == 0)
          __hip_atomic_store(&flags[j << 5], (unsigned)(t + 1),
                             __ATOMIC_RELAXED, __HIP_MEMORY_SCOPE_AGENT);
      }

      // hs in [t][b] layout, coherent (consumed by concurrent GEMM workers)
      st_coh_b16(hs + ((size_t)((t << 4) + b) << 10) + cg, (unsigned)f2bf(hprev));
      if (t < 255) {
        const unsigned short* gr = gi + ((size_t)b * 256 + (t + 1)) * 3072;
        ir = bf2f(gr[cg]); iz = bf2f(gr[1024 + cg]); inn = bf2f(gr[2048 + cg]);
      }
    }
    // final drain + done sentinel
    asm volatile("s_waitcnt vmcnt(0)" ::: "memory");
    __syncthreads();
    if (tid == 0)
      __hip_atomic_store(&flags[j << 5], 1024u, __ATOMIC_RELAXED, __HIP_MEMORY_SCOPE_AGENT);
    return;
  }

  // ============ logits: persistent workers + atomic tile queue ==============
  __shared__ unsigned qk_sh;
  const int wm = wave >> 2, wn = wave & 3;          // 2 x 4 waves
  const int lr = lane & 15, ko = (lane >> 4) << 4;
  const int arow = tid >> 1, ahalf = (tid & 1) << 5;
  const int awz0 = ((arow << 6) + ahalf) ^ ((arow & 12) << 2);
  const int awz1 = ((arow << 6) + ahalf + 16) ^ ((arow & 12) << 2);
  const int srow = tid >> 2, skb = (tid & 3) << 4;
  const int lq = (lane >> 4) << 2;

  for (;;) {
    if (tid == 0)
      qk_sh = __hip_atomic_fetch_add(qhead, 1u, __ATOMIC_RELAXED, __HIP_MEMORY_SCOPE_AGENT);
    __syncthreads();
    const unsigned k = qk_sh;
    if (k >= 2000u) return;
    const int bm = (int)(k / 125), bn = (int)(k % 125);
    const long row0 = (long)bm << 8, col0 = (long)bn << 8;

    {   // wait for hs rows [16bm, 16bm+16) to be globally visible
      unsigned thr = (unsigned)(16 * bm + 17); if (thr > 255u) thr = 1024u;
      if (wave == 0) {
        long guard = 0;
        for (;;) {
          const unsigned f = __hip_atomic_load(&flags[lane << 5], __ATOMIC_RELAXED,
                                               __HIP_MEMORY_SCOPE_AGENT);
          if (__all(f >= thr)) break;
          __builtin_amdgcn_s_sleep(32);
          if (++guard > (1L << 22)) break;
        }
      }
      __syncthreads();
    }

    const char* Ab = (const char*)hs + ((row0 + arow) << 11) + ahalf;
    auto stageB = [&](int sp, int rr) {
      const int row = (rr << 7) + srow;
      const int kbu = skb ^ ((row & 12) << 2);
      const char* g = (const char*)WoutB + ((col0 + row) << 11) + (sp << 6) + kbu;
      char* l = lds + ((sp & 1) << 15) + 16384 + (rr << 13) + (wave << 10);
      GLDS(g, l);
    };
    auto rdA = [&](int buf, int mrep) {
      const int rt = (wm << 7) + (mrep << 4) + lr;
      const int a = (rt << 6) + ko;
      return *(const bf16x8*)(lds + (buf << 15) + (a ^ ((rt & 12) << 2)));
    };
    auto rdB = [&](int buf, int nrep) {
      const int rt = (wn << 6) + (nrep << 4) + lr;
      const int a = (rt << 6) + ko;
      return *(const bf16x8*)(lds + (buf << 15) + 16384 + (a ^ ((rt & 12) << 2)));
    };

    f32x4 acc[8][4] = {};
    i32x4 rA0 = ld_coh_b128(Ab);                     // A(0) -> regs
    i32x4 rA1 = ld_coh_b128(Ab + 16);
    stageB(0, 0); stageB(0, 1);

    for (int s = 0; s < 32; ++s) {
      const int buf = s & 1;
      if (s < 31) {
        stageB(s + 1, 0); stageB(s + 1, 1);          // into buf^1
        asm volatile("s_waitcnt vmcnt(2)" ::: "memory");   // A(s) regs + B(s) LDS done
      } else {
        asm volatile("s_waitcnt vmcnt(0)" ::: "memory");
      }
      __builtin_amdgcn_sched_barrier(0);
      *(i32x4*)(lds + (buf << 15) + awz0) = rA0;     // commit A(s) swizzled
      *(i32x4*)(lds + (buf << 15) + awz1) = rA1;
      if (s < 31) {
        rA0 = ld_coh_b128(Ab + ((s + 1) << 6));      // A(s+1) -> regs
        rA1 = ld_coh_b128(Ab + ((s + 1) << 6) + 16);
      }
      asm volatile("s_waitcnt lgkmcnt(0)" ::: "memory");
      __builtin_amdgcn_sched_barrier(0);
      __builtin_amdgcn_s_barrier();                  // buf fully valid

      bf16x8 bfr[4], af[4], af2[4];
#pragma unroll
      for (int n = 0; n < 4; ++n) bfr[n] = rdB(buf, n);
#pragma unroll
      for (int m = 0; m < 4; ++m) af[m] = rdA(buf, m);
      asm volatile("s_waitcnt lgkmcnt(0)" ::: "memory");
      __builtin_amdgcn_sched_barrier(0);
      __builtin_amdgcn_s_setprio(1);
#pragma unroll
      for (int m = 0; m < 4; ++m)
#pragma unroll
        for (int n = 0; n < 4; ++n)
          acc[m][n] = __builtin_amdgcn_mfma_f32_16x16x32_bf16(af[m], bfr[n], acc[m][n], 0, 0, 0);
      __builtin_amdgcn_s_setprio(0);
#pragma unroll
      for (int m = 0; m < 4; ++m) af2[m] = rdA(buf, m + 4);
      asm volatile("s_waitcnt lgkmcnt(0)" ::: "memory");
      __builtin_amdgcn_sched_barrier(0);
      __builtin_amdgcn_s_barrier();                  // all reads of buf done
      __builtin_amdgcn_s_setprio(1);
#pragma unroll
      for (int m = 0; m < 4; ++m)
#pragma unroll
        for (int n = 0; n < 4; ++n)
          acc[m + 4][n] = __builtin_amdgcn_mfma_f32_16x16x32_bf16(af2[m], bfr[n], acc[m + 4][n], 0, 0, 0);
      __builtin_amdgcn_s_setprio(0);
    }

    // epilogue: A row ar = t*16+b  ->  C row = b*256+t
#pragma unroll
    for (int mr = 0; mr < 8; ++mr) {
#pragma unroll
      for (int q = 0; q < 4; ++q) {
        const int ar = (int)row0 + (wm << 7) + (mr << 4) + lq + q;
        const int tt = ar >> 4, bb = ar & 15;
        float* crow = out + ((size_t)bb * 256 + tt) * 32000;
#pragma unroll
        for (int nr = 0; nr < 4; ++nr) {
          const long cc = col0 + (wn << 6) + (nr << 4) + lr;
          crow[cc] = acc[mr][nr][q] + bout[cc];
        }
      }
    }
    __syncthreads();   // qk_sh / LDS safe for next pop
  }
}

// ---------- launch ----------
extern "C" void kernel_launch(void* const* d_in, const int* in_sizes, int n_in,
                              void* d_out, int out_size, void* d_ws, size_t ws_size,
                              hipStream_t stream) {
  const float* z     = (const float*)d_in[0];
  const int*   x     = (const int*)d_in[1];
  const float* emb   = (const float*)d_in[2];
  const float* Winit = (const float*)d_in[3];
  const float* binit = (const float*)d_in[4];
  const float* Wih   = (const float*)d_in[5];
  const float* Whh   = (const float*)d_in[6];
  const float* bih   = (const float*)d_in[7];
  const float* bhh   = (const float*)d_in[8];
  const float* Wout  = (const float*)d_in[9];
  const float* bout  = (const float*)d_in[10];
  float* out = (float*)d_out;

  char* ws = (char*)d_ws;
  size_t off = 0;
  auto alloc = [&](size_t bytes) { void* p = ws + off; off += (bytes + 255) & ~(size_t)255; return p; };
  unsigned int*   flags = (unsigned int*)alloc(64 * 128);
  unsigned int*   qhead = (unsigned int*)alloc(256);
  unsigned short* xe    = (unsigned short*)alloc((size_t)4096 * 512 * 2);
  unsigned short* WihB  = (unsigned short*)alloc((size_t)3072 * 512 * 2);
  unsigned short* WoutB = (unsigned short*)alloc((size_t)32000 * 1024 * 2);
  unsigned short* giB   = (unsigned short*)alloc((size_t)4096 * 3072 * 2);
  unsigned short* hsB   = (unsigned short*)alloc((size_t)4096 * 1024 * 2);
  float*          h0f   = (float*)alloc((size_t)16 * 1024 * 4);
  unsigned short* hb16  = (unsigned short*)alloc((size_t)2 * 16 * 1024 * 2);
  (void)ws_size; (void)in_sizes; (void)n_in; (void)out_size;

  hipMemsetAsync(flags, 0, 64 * 128 + 256, stream);   // flags + qhead (contiguous)

  // prep: gather + h0 + W_ih conv + W_out conv
  prep<<<dim3(4160), 256, 0, stream>>>(x, emb, xe, z, Winit, binit, h0f, hb16,
                                       Wih, WihB, Wout, WoutB);

  // gi = xe @ W_ih^T + b_ih   [4096, 3072] bf16
  gemm_bt<<<dim3(32 * 24), 256, 0, stream>>>(xe, WihB, bih, giB, 4096, 3072, 512);

  // fused: GRU (blocks 0-63) + 192 persistent logits workers (64-255)
  mega<<<dim3(256), 512, 0, stream>>>(Whh, bhh, giB, h0f, hb16, hsB, flags, qhead,
                                      WoutB, bout, out);
}